// Round 1
// baseline (633.755 us; speedup 1.0000x reference)
//
#include <hip/hip_runtime.h>
#include <hip/hip_bf16.h>

#define H 128
#define NEG 0.01f

typedef __bf16 bf16;
typedef bf16 bf16x4 __attribute__((ext_vector_type(4)));
typedef bf16 bf16x8 __attribute__((ext_vector_type(8)));
typedef float f32x4 __attribute__((ext_vector_type(4)));
typedef float f32x2 __attribute__((ext_vector_type(2)));
typedef unsigned int u32;

// ---- fp8 e4m3 (OCP on gfx950) pack/unpack: 8 elems <-> 8 bytes (uint2) ----
__device__ __forceinline__ void dec8(uint2 p, float f[8]) {
    f32x2 a = __builtin_amdgcn_cvt_pk_f32_fp8(p.x, false);
    f32x2 b = __builtin_amdgcn_cvt_pk_f32_fp8(p.x, true);
    f32x2 c = __builtin_amdgcn_cvt_pk_f32_fp8(p.y, false);
    f32x2 d = __builtin_amdgcn_cvt_pk_f32_fp8(p.y, true);
    f[0] = a[0]; f[1] = a[1]; f[2] = b[0]; f[3] = b[1];
    f[4] = c[0]; f[5] = c[1]; f[6] = d[0]; f[7] = d[1];
}
__device__ __forceinline__ uint2 enc8(const float f[8]) {
    int lo = 0, hi = 0;
    lo = __builtin_amdgcn_cvt_pk_fp8_f32(f[0], f[1], lo, false);
    lo = __builtin_amdgcn_cvt_pk_fp8_f32(f[2], f[3], lo, true);
    hi = __builtin_amdgcn_cvt_pk_fp8_f32(f[4], f[5], hi, false);
    hi = __builtin_amdgcn_cvt_pk_fp8_f32(f[6], f[7], hi, true);
    uint2 r; r.x = (u32)lo; r.y = (u32)hi; return r;
}

// ---------------- weight pre-transpose (f32 row-major -> bf16 col-major) ----------------

__global__ void k_prepw(const float* __restrict__ Wn, const float* __restrict__ Wg,
                        bf16* __restrict__ WnT, bf16* __restrict__ WgT) {
    int i = blockIdx.x * 256 + threadIdx.x;
    if (i < 256 * 128) {            // WnT[n][k] = Wn[k][n], K=256, Ncol=128
        int n = i >> 8, k = i & 255;
        WnT[i] = (bf16)Wn[k * 128 + n];
    }
    if (i < 128 * 128) {            // WgT[n][k] = Wg[k][n], 128x128
        int n = i >> 7, k = i & 127;
        WgT[i] = (bf16)Wg[k * 128 + n];
    }
}

// ---------------- CSR build ----------------

__global__ void k_hist(const int* __restrict__ dst, int* __restrict__ cnt, int e) {
    int i = blockIdx.x * 256 + threadIdx.x;
    if (i < e) atomicAdd(&cnt[dst[i]], 1);
}

__global__ void k_scan1(const int* __restrict__ cnt, int* __restrict__ part, int n) {
    __shared__ int sh[256];
    int i = blockIdx.x * 256 + threadIdx.x;
    sh[threadIdx.x] = (i < n) ? cnt[i] : 0;
    __syncthreads();
    for (int off = 128; off > 0; off >>= 1) {
        if (threadIdx.x < off) sh[threadIdx.x] += sh[threadIdx.x + off];
        __syncthreads();
    }
    if (threadIdx.x == 0) part[blockIdx.x] = sh[0];
}

__global__ void k_scan2(int* part, int nblk) {
    __shared__ int sh[256];
    int t = threadIdx.x;
    sh[t] = (t < nblk) ? part[t] : 0;
    __syncthreads();
    for (int off = 1; off < 256; off <<= 1) {
        int v = (t >= off) ? sh[t - off] : 0;
        __syncthreads();
        sh[t] += v;
        __syncthreads();
    }
    if (t < nblk) part[t] = (t == 0) ? 0 : sh[t - 1];
}

__global__ void k_scan3(const int* __restrict__ cnt, const int* __restrict__ part,
                        int* __restrict__ row_ptr, int* __restrict__ nxt, int n, int e) {
    __shared__ int sh[256];
    int t = threadIdx.x;
    int i = blockIdx.x * 256 + t;
    sh[t] = (i < n) ? cnt[i] : 0;
    __syncthreads();
    for (int off = 1; off < 256; off <<= 1) {
        int v = (t >= off) ? sh[t - off] : 0;
        __syncthreads();
        sh[t] += v;
        __syncthreads();
    }
    int excl = part[blockIdx.x] + ((t == 0) ? 0 : sh[t - 1]);
    if (i < n) { row_ptr[i] = excl; nxt[i] = excl; }
    if (i == 0) row_ptr[n] = e;
}

__global__ void k_fill(const int* __restrict__ src, const int* __restrict__ dst,
                       int* __restrict__ nxt, int* __restrict__ ssrc, int e) {
    int i = blockIdx.x * 256 + threadIdx.x;
    if (i < e) {
        int p = atomicAdd(&nxt[dst[i]], 1);
        ssrc[p] = src[i];
    }
}

// ---------------- agg0: hs[v] = (sum_{u->v} h0[u]) / deg[v]  (fp8 in, fp8 out) ----------------
// 1 wave/node, 4 groups of 16 lanes, 4 edges in flight/group

__global__ __launch_bounds__(256)
void k_agg0(const uint2* __restrict__ hg, const int* __restrict__ row_ptr,
            const int* __restrict__ ssrc, const float* __restrict__ deg,
            uint2* __restrict__ hs, int n) {
    int v = blockIdx.x * 4 + (threadIdx.x >> 6);
    if (v >= n) return;
    int lane = threadIdx.x & 63;
    int g = lane >> 4, sub = lane & 15;
    int e0 = row_ptr[v], e1 = row_ptr[v + 1];
    float d = deg[v];
    float acc[8];
#pragma unroll
    for (int k = 0; k < 8; k++) acc[k] = 0.f;
    for (int base = e0; base < e1; base += 16) {
        int mye = base + g * 4;
        int idx[4]; float w[4];
#pragma unroll
        for (int j = 0; j < 4; j++) {
            int e = mye + j;
            w[j] = (e < e1) ? 1.0f : 0.0f;
            idx[j] = ssrc[e < e1 ? e : e1 - 1];
        }
        uint2 x0 = hg[(size_t)idx[0] * 16 + sub];
        uint2 x1 = hg[(size_t)idx[1] * 16 + sub];
        uint2 x2 = hg[(size_t)idx[2] * 16 + sub];
        uint2 x3 = hg[(size_t)idx[3] * 16 + sub];
        float f0[8], f1[8], f2[8], f3[8];
        dec8(x0, f0); dec8(x1, f1); dec8(x2, f2); dec8(x3, f3);
#pragma unroll
        for (int k = 0; k < 8; k++) acc[k] = fmaf(w[0], f0[k], acc[k]);
#pragma unroll
        for (int k = 0; k < 8; k++) acc[k] = fmaf(w[1], f1[k], acc[k]);
#pragma unroll
        for (int k = 0; k < 8; k++) acc[k] = fmaf(w[2], f2[k], acc[k]);
#pragma unroll
        for (int k = 0; k < 8; k++) acc[k] = fmaf(w[3], f3[k], acc[k]);
    }
#pragma unroll
    for (int k = 0; k < 8; k++) acc[k] += __shfl_xor(acc[k], 16);
#pragma unroll
    for (int k = 0; k < 8; k++) acc[k] += __shfl_xor(acc[k], 32);
    if (g == 0) {
        float r = 1.0f / d;
        float o[8];
#pragma unroll
        for (int k = 0; k < 8; k++) o[k] = acc[k] * r;
        hs[(size_t)v * 16 + sub] = enc8(o);
    }
}

// ---------------- GEMM0: h0_fp8[M,128] = A_f32[M,256] @ Wn + bn, fused colsum ----------------

__global__ __launch_bounds__(256)
void k_gemm0(const float* __restrict__ A, const bf16* __restrict__ WnT,
             const float* __restrict__ bias, uint2* __restrict__ Cg,
             float* __restrict__ colsum, int M) {
    constexpr int K = 256, BM = 64, BN = 128, BK = 64, LDT = BK + 8;
    __shared__ alignas(16) bf16 As[BM][LDT];
    __shared__ alignas(16) bf16 Bs[BN][LDT];
    __shared__ float cs[128];
    const int tid = threadIdx.x;
    const int wave = tid >> 6, lane = tid & 63;
    const int sub = lane & 15, rg = lane >> 4;
    const int blockRow = blockIdx.x * BM;
    if (tid < 128) cs[tid] = 0.f;

    f32x4 acc[8];
#pragma unroll
    for (int t = 0; t < 8; t++) acc[t] = (f32x4){0.f, 0.f, 0.f, 0.f};

    for (int k0 = 0; k0 < K; k0 += BK) {
#pragma unroll
        for (int it = 0; it < 4; it++) {
            int s = it * 256 + tid;
            int row = s >> 4, f4 = (s & 15) * 4;
            int grow = blockRow + row; if (grow > M - 1) grow = M - 1;
            const float4 v = *(const float4*)(A + (size_t)grow * K + k0 + f4);
            bf16x4 w = { (bf16)v.x, (bf16)v.y, (bf16)v.z, (bf16)v.w };
            *(bf16x4*)&As[row][f4] = w;
        }
        // B: straight bf16 copy from pre-transposed WnT[col][k]
#pragma unroll
        for (int it = 0; it < 4; it++) {
            int s = it * 256 + tid;
            int row = s >> 3, ch = (s & 7) * 8;
            *(bf16x8*)&Bs[row][ch] = *(const bf16x8*)(WnT + (size_t)row * 256 + k0 + ch);
        }
        __syncthreads();
#pragma unroll
        for (int kk = 0; kk < BK; kk += 32) {
            bf16x8 af = *(const bf16x8*)&As[wave * 16 + sub][kk + rg * 8];
#pragma unroll
            for (int t = 0; t < 8; t++) {
                bf16x8 bfv = *(const bf16x8*)&Bs[t * 16 + sub][kk + rg * 8];
                acc[t] = __builtin_amdgcn_mfma_f32_16x16x32_bf16(af, bfv, acc[t], 0, 0, 0);
            }
        }
        __syncthreads();
    }
    // epilogue: bias, colsum, restage tile into LDS (Bs reused) for fp8 packing
    bf16* stg = (bf16*)&Bs[0][0];       // viewed as [64][136]
    const int rbase0 = wave * 16 + rg * 4;
    float lsum[8];
#pragma unroll
    for (int t = 0; t < 8; t++) lsum[t] = 0.f;
#pragma unroll
    for (int r = 0; r < 4; r++) {
        int rowt = rbase0 + r;
        if (blockRow + rowt < M) {
#pragma unroll
            for (int t = 0; t < 8; t++) {
                int col = t * 16 + sub;
                float val = acc[t][r] + bias[col];
                lsum[t] += val;
                stg[rowt * 136 + col] = (bf16)val;
            }
        }
    }
#pragma unroll
    for (int t = 0; t < 8; t++) {
        lsum[t] += __shfl_xor(lsum[t], 16);
        lsum[t] += __shfl_xor(lsum[t], 32);
    }
    if (rg == 0) {
#pragma unroll
        for (int t = 0; t < 8; t++) atomicAdd(&cs[t * 16 + sub], lsum[t]);
    }
    __syncthreads();
    if (tid < 128) atomicAdd(&colsum[tid], cs[tid]);
#pragma unroll
    for (int it = 0; it < 4; it++) {
        int s = it * 256 + tid;
        int row = s >> 4, cg = s & 15;
        int grow = blockRow + row;
        if (grow < M) {
            float f[8];
#pragma unroll
            for (int k = 0; k < 8; k++) f[k] = (float)stg[row * 136 + cg * 8 + k];
            Cg[(size_t)grow * 16 + cg] = enc8(f);
        }
    }
}

// ---------------- fused layer: A-tile = aggregation, then GEMM + leakyrelu ----------------
// agg[v] = sum_{u->v} hsin[u] + hsin[v]*deg[v];  out = leakyrelu(agg @ Wgcn + b)
// hsout[v] = fp8(out/deg[v]) when WRITE_NEXT.  hsin/hsout are distinct buffers (ping-pong):
// blocks read arbitrary hsin rows while writing their own hsout rows -> no race.

template<bool WRITE_NEXT>
__global__ __launch_bounds__(256)
void k_gemmL(const uint2* __restrict__ hsin, const int* __restrict__ row_ptr,
             const int* __restrict__ ssrc, const float* __restrict__ deg,
             const bf16* __restrict__ WgT, const float* __restrict__ bias,
             uint2* __restrict__ hsout, float* __restrict__ colsum, int M) {
    constexpr int BM = 64, BN = 128, BK = 128, LDT = BK + 8;
    __shared__ alignas(16) bf16 As[BM][LDT];
    __shared__ alignas(16) bf16 Bs[BN][LDT];
    __shared__ float cs[128];
    const int tid = threadIdx.x;
    const int wave = tid >> 6, lane = tid & 63;
    const int sub = lane & 15, rg = lane >> 4;
    const int blockRow = blockIdx.x * BM;
    if (tid < 128) cs[tid] = 0.f;

    // ---- B staging: straight bf16 copy from pre-transposed WgT[col][k] ----
#pragma unroll
    for (int it = 0; it < 8; it++) {
        int s = it * 256 + tid;
        int row = s >> 4, ch = (s & 15) * 8;
        *(bf16x8*)&Bs[row][ch] = *(const bf16x8*)(WgT + (size_t)row * 128 + ch);
    }

    // ---- A-tile via fused aggregation: 16 groups x 16 lanes, 4 nodes/group ----
    {
        const int gid = tid >> 4, s16 = tid & 15;
        for (int i = 0; i < 4; i++) {
            int rowt = gid * 4 + i;
            int v = blockRow + rowt;
            float acc[8];
#pragma unroll
            for (int k = 0; k < 8; k++) acc[k] = 0.f;
            if (v < M) {
                int e0 = row_ptr[v], e1 = row_ptr[v + 1];
                uint2 sv = hsin[(size_t)v * 16 + s16];   // self row, issued early
                float d = deg[v];
                for (int base = e0; base < e1; base += 4) {
                    int idx[4]; float w[4];
#pragma unroll
                    for (int j = 0; j < 4; j++) {
                        int e = base + j;
                        w[j] = (e < e1) ? 1.0f : 0.0f;
                        idx[j] = ssrc[e < e1 ? e : e1 - 1];
                    }
                    uint2 x0 = hsin[(size_t)idx[0] * 16 + s16];
                    uint2 x1 = hsin[(size_t)idx[1] * 16 + s16];
                    uint2 x2 = hsin[(size_t)idx[2] * 16 + s16];
                    uint2 x3 = hsin[(size_t)idx[3] * 16 + s16];
                    float f0[8], f1[8], f2[8], f3[8];
                    dec8(x0, f0); dec8(x1, f1); dec8(x2, f2); dec8(x3, f3);
#pragma unroll
                    for (int k = 0; k < 8; k++) acc[k] = fmaf(w[0], f0[k], acc[k]);
#pragma unroll
                    for (int k = 0; k < 8; k++) acc[k] = fmaf(w[1], f1[k], acc[k]);
#pragma unroll
                    for (int k = 0; k < 8; k++) acc[k] = fmaf(w[2], f2[k], acc[k]);
#pragma unroll
                    for (int k = 0; k < 8; k++) acc[k] = fmaf(w[3], f3[k], acc[k]);
                }
                float fs[8];
                dec8(sv, fs);
#pragma unroll
                for (int k = 0; k < 8; k++) acc[k] = fmaf(fs[k], d, acc[k]);
            }
            bf16x8 wv;
#pragma unroll
            for (int k = 0; k < 8; k++) wv[k] = (bf16)acc[k];
            *(bf16x8*)&As[rowt][s16 * 8] = wv;
        }
    }
    __syncthreads();

    // ---- MFMA ----
    f32x4 acc[8];
#pragma unroll
    for (int t = 0; t < 8; t++) acc[t] = (f32x4){0.f, 0.f, 0.f, 0.f};
#pragma unroll
    for (int kk = 0; kk < BK; kk += 32) {
        bf16x8 af = *(const bf16x8*)&As[wave * 16 + sub][kk + rg * 8];
#pragma unroll
        for (int t = 0; t < 8; t++) {
            bf16x8 bfv = *(const bf16x8*)&Bs[t * 16 + sub][kk + rg * 8];
            acc[t] = __builtin_amdgcn_mfma_f32_16x16x32_bf16(af, bfv, acc[t], 0, 0, 0);
        }
    }
    __syncthreads();

    // ---- epilogue: bias + leakyrelu + colsum (+ fp8 pack of val/deg) ----
    bf16* stg = (bf16*)&Bs[0][0];       // viewed as [64][136]
    const int rbase0 = wave * 16 + rg * 4;
    float lsum[8];
#pragma unroll
    for (int t = 0; t < 8; t++) lsum[t] = 0.f;
#pragma unroll
    for (int r = 0; r < 4; r++) {
        int rowt = rbase0 + r;
        int grow = blockRow + rowt;
        if (grow < M) {
            float rd = WRITE_NEXT ? (1.0f / deg[grow]) : 0.f;
#pragma unroll
            for (int t = 0; t < 8; t++) {
                int col = t * 16 + sub;
                float val = acc[t][r] + bias[col];
                val = (val > 0.f) ? val : NEG * val;
                lsum[t] += val;
                if (WRITE_NEXT) stg[rowt * 136 + col] = (bf16)(val * rd);
            }
        }
    }
#pragma unroll
    for (int t = 0; t < 8; t++) {
        lsum[t] += __shfl_xor(lsum[t], 16);
        lsum[t] += __shfl_xor(lsum[t], 32);
    }
    if (rg == 0) {
#pragma unroll
        for (int t = 0; t < 8; t++) atomicAdd(&cs[t * 16 + sub], lsum[t]);
    }
    __syncthreads();
    if (tid < 128) atomicAdd(&colsum[tid], cs[tid]);
    if (WRITE_NEXT) {
#pragma unroll
        for (int it = 0; it < 4; it++) {
            int s = it * 256 + tid;
            int row = s >> 4, cg = s & 15;
            int grow = blockRow + row;
            if (grow < M) {
                float f[8];
#pragma unroll
                for (int k = 0; k < 8; k++) f[k] = (float)stg[row * 136 + cg * 8 + k];
                hsout[(size_t)grow * 16 + cg] = enc8(f);
            }
        }
    }
}

// ---------------- finisher ----------------

__global__ void k_final(const float* __restrict__ colsum, const float* __restrict__ Wpred,
                        const float* __restrict__ bpred, const float* __restrict__ Wcls,
                        const float* __restrict__ bcls, float* __restrict__ out, int n) {
    __shared__ float g[512];
    __shared__ float g2[128];
    __shared__ float lg[2];
    int t = threadIdx.x;  // 128 threads
    float invn = 1.0f / (float)n;
    for (int i = t; i < 512; i += 128) g[i] = colsum[i] * invn;
    __syncthreads();
    float acc = bpred[t];
    for (int i = 0; i < 512; i++) acc += g[i] * Wpred[i * 128 + t];
    g2[t] = acc;
    __syncthreads();
    if (t < 2) {
        float l = bcls[t];
        for (int j = 0; j < 128; j++) l += g2[j] * Wcls[j * 2 + t];
        lg[t] = l;
    }
    __syncthreads();
    if (t == 0) {
        float m = fmaxf(lg[0], lg[1]);
        float e0 = expf(lg[0] - m), e1 = expf(lg[1] - m);
        float s = e0 + e1;
        out[0] = e0 / s;
        out[1] = e1 / s;
    }
}

// ---------------- launch ----------------

extern "C" void kernel_launch(void* const* d_in, const int* in_sizes, int n_in,
                              void* d_out, int out_size, void* d_ws, size_t ws_size,
                              hipStream_t stream) {
    const float* node_feat = (const float*)d_in[0];
    const float* degree = (const float*)d_in[3];
    const float* Wn     = (const float*)d_in[4];
    const float* bn     = (const float*)d_in[5];
    const float* Wgcn   = (const float*)d_in[8];
    const float* bgcn   = (const float*)d_in[9];
    const float* Wpred  = (const float*)d_in[10];
    const float* bpred  = (const float*)d_in[11];
    const float* Wcls   = (const float*)d_in[12];
    const float* bcls   = (const float*)d_in[13];
    const int*   src    = (const int*)d_in[14];
    const int*   dst    = (const int*)d_in[15];
    float* out = (float*)d_out;

    const int N = in_sizes[3];
    const int E = in_sizes[14];
    (void)n_in; (void)out_size; (void)ws_size;

    char* p = (char*)d_ws;
    auto carve = [&](size_t bytes) { char* r = p; p += (bytes + 255) & ~(size_t)255; return r; };
    uint2* h0g    = (uint2*)carve((size_t)N * H);       // fp8 h0 gather table (128 B/row)
    uint2* hsb0   = (uint2*)carve((size_t)N * H);       // fp8 pre-scaled hidden, ping
    uint2* hsb1   = (uint2*)carve((size_t)N * H);       // fp8 pre-scaled hidden, pong
    bf16*  WnT    = (bf16*)carve((size_t)256 * 128 * 2);
    bf16*  WgT    = (bf16*)carve((size_t)128 * 128 * 2);
    int*   cnt    = (int*)carve((size_t)N * 4);
    int*   row_ptr= (int*)carve((size_t)(N + 1) * 4);
    int*   nxt    = (int*)carve((size_t)N * 4);
    int*   ssrc   = (int*)carve((size_t)E * 4);
    int*   part   = (int*)carve(256 * 4);
    float* colsum = (float*)carve(512 * 4);

    const int nblk = (N + 255) / 256;
    hipMemsetAsync(cnt, 0, (size_t)N * 4, stream);
    hipMemsetAsync(colsum, 0, 512 * 4, stream);

    k_prepw<<<128, 256, 0, stream>>>(Wn, Wgcn, WnT, WgT);

    k_hist<<<(E + 255) / 256, 256, 0, stream>>>(dst, cnt, E);
    k_scan1<<<nblk, 256, 0, stream>>>(cnt, part, N);
    k_scan2<<<1, 256, 0, stream>>>(part, nblk);
    k_scan3<<<nblk, 256, 0, stream>>>(cnt, part, row_ptr, nxt, N, E);
    k_fill<<<(E + 255) / 256, 256, 0, stream>>>(src, dst, nxt, ssrc, E);

    const int gblk = (N + 63) / 64;
    const int ablk = (N + 3) / 4;

    // h0 = node_feat @ Wn + bn  (fp8 out + colsum[0:128))
    k_gemm0<<<gblk, 256, 0, stream>>>(node_feat, WnT, bn, h0g, colsum, N);
    // fusion: hsb0[v] = (sum_{u->v} h0[u]) / deg[v]
    k_agg0<<<ablk, 256, 0, stream>>>(h0g, row_ptr, ssrc, degree, hsb0, N);

    // fused layers: (gather+self) -> gemm -> leakyrelu -> colsum (+ next hs, ping-pong)
    k_gemmL<true ><<<gblk, 256, 0, stream>>>(hsb0, row_ptr, ssrc, degree, WgT, bgcn, hsb1, colsum + 1 * H, N);
    k_gemmL<true ><<<gblk, 256, 0, stream>>>(hsb1, row_ptr, ssrc, degree, WgT, bgcn, hsb0, colsum + 2 * H, N);
    k_gemmL<false><<<gblk, 256, 0, stream>>>(hsb0, row_ptr, ssrc, degree, WgT, bgcn, hsb1, colsum + 3 * H, N);

    k_final<<<1, 128, 0, stream>>>(colsum, Wpred, bpred, Wcls, bcls, out, N);
}

// Round 3
// 595.063 us; speedup vs baseline: 1.0650x; 1.0650x over previous
//
#include <hip/hip_runtime.h>
#include <hip/hip_bf16.h>

#define H 128
#define NEG 0.01f

typedef __bf16 bf16;
typedef bf16 bf16x4 __attribute__((ext_vector_type(4)));
typedef bf16 bf16x8 __attribute__((ext_vector_type(8)));
typedef float f32x4 __attribute__((ext_vector_type(4)));
typedef float f32x2 __attribute__((ext_vector_type(2)));
typedef unsigned int u32;

// ---- fp8 e4m3 (OCP on gfx950) pack/unpack: 16 elems <-> 16 bytes (uint4) ----
__device__ __forceinline__ void dec16(uint4 p, float f[16]) {
    f32x2 a0 = __builtin_amdgcn_cvt_pk_f32_fp8(p.x, false);
    f32x2 a1 = __builtin_amdgcn_cvt_pk_f32_fp8(p.x, true);
    f32x2 b0 = __builtin_amdgcn_cvt_pk_f32_fp8(p.y, false);
    f32x2 b1 = __builtin_amdgcn_cvt_pk_f32_fp8(p.y, true);
    f32x2 c0 = __builtin_amdgcn_cvt_pk_f32_fp8(p.z, false);
    f32x2 c1 = __builtin_amdgcn_cvt_pk_f32_fp8(p.z, true);
    f32x2 d0 = __builtin_amdgcn_cvt_pk_f32_fp8(p.w, false);
    f32x2 d1 = __builtin_amdgcn_cvt_pk_f32_fp8(p.w, true);
    f[0]=a0[0];  f[1]=a0[1];  f[2]=a1[0];  f[3]=a1[1];
    f[4]=b0[0];  f[5]=b0[1];  f[6]=b1[0];  f[7]=b1[1];
    f[8]=c0[0];  f[9]=c0[1];  f[10]=c1[0]; f[11]=c1[1];
    f[12]=d0[0]; f[13]=d0[1]; f[14]=d1[0]; f[15]=d1[1];
}
__device__ __forceinline__ uint4 enc16(const float f[16]) {
    int a = 0, b = 0, c = 0, d = 0;
    a = __builtin_amdgcn_cvt_pk_fp8_f32(f[0],  f[1],  a, false);
    a = __builtin_amdgcn_cvt_pk_fp8_f32(f[2],  f[3],  a, true);
    b = __builtin_amdgcn_cvt_pk_fp8_f32(f[4],  f[5],  b, false);
    b = __builtin_amdgcn_cvt_pk_fp8_f32(f[6],  f[7],  b, true);
    c = __builtin_amdgcn_cvt_pk_fp8_f32(f[8],  f[9],  c, false);
    c = __builtin_amdgcn_cvt_pk_fp8_f32(f[10], f[11], c, true);
    d = __builtin_amdgcn_cvt_pk_fp8_f32(f[12], f[13], d, false);
    d = __builtin_amdgcn_cvt_pk_fp8_f32(f[14], f[15], d, true);
    uint4 r; r.x = (u32)a; r.y = (u32)b; r.z = (u32)c; r.w = (u32)d; return r;
}

// ---------------- weight pre-transpose (f32 row-major -> bf16 col-major) ----------------

__global__ void k_prepw(const float* __restrict__ Wn, const float* __restrict__ Wg,
                        bf16* __restrict__ WnT, bf16* __restrict__ WgT) {
    int i = blockIdx.x * 256 + threadIdx.x;
    if (i < 256 * 128) {            // WnT[n][k] = Wn[k][n], K=256, Ncol=128
        int n = i >> 8, k = i & 255;
        WnT[i] = (bf16)Wn[k * 128 + n];
    }
    if (i < 128 * 128) {            // WgT[n][k] = Wg[k][n], 128x128
        int n = i >> 7, k = i & 127;
        WgT[i] = (bf16)Wg[k * 128 + n];
    }
}

// ---------------- CSR build ----------------

__global__ void k_hist(const int* __restrict__ dst, int* __restrict__ cnt, int e) {
    int i = blockIdx.x * 256 + threadIdx.x;
    if (i < e) atomicAdd(&cnt[dst[i]], 1);
}

__global__ void k_scan1(const int* __restrict__ cnt, int* __restrict__ part, int n) {
    __shared__ int sh[256];
    int i = blockIdx.x * 256 + threadIdx.x;
    sh[threadIdx.x] = (i < n) ? cnt[i] : 0;
    __syncthreads();
    for (int off = 128; off > 0; off >>= 1) {
        if (threadIdx.x < off) sh[threadIdx.x] += sh[threadIdx.x + off];
        __syncthreads();
    }
    if (threadIdx.x == 0) part[blockIdx.x] = sh[0];
}

__global__ void k_scan2(int* part, int nblk) {
    __shared__ int sh[256];
    int t = threadIdx.x;
    sh[t] = (t < nblk) ? part[t] : 0;
    __syncthreads();
    for (int off = 1; off < 256; off <<= 1) {
        int v = (t >= off) ? sh[t - off] : 0;
        __syncthreads();
        sh[t] += v;
        __syncthreads();
    }
    if (t < nblk) part[t] = (t == 0) ? 0 : sh[t - 1];
}

__global__ void k_scan3(const int* __restrict__ cnt, const int* __restrict__ part,
                        int* __restrict__ row_ptr, int* __restrict__ nxt, int n, int e) {
    __shared__ int sh[256];
    int t = threadIdx.x;
    int i = blockIdx.x * 256 + t;
    sh[t] = (i < n) ? cnt[i] : 0;
    __syncthreads();
    for (int off = 1; off < 256; off <<= 1) {
        int v = (t >= off) ? sh[t - off] : 0;
        __syncthreads();
        sh[t] += v;
        __syncthreads();
    }
    int excl = part[blockIdx.x] + ((t == 0) ? 0 : sh[t - 1]);
    if (i < n) { row_ptr[i] = excl; nxt[i] = excl; }
    if (i == 0) row_ptr[n] = e;
}

__global__ void k_fill(const int* __restrict__ src, const int* __restrict__ dst,
                       int* __restrict__ nxt, int* __restrict__ ssrc, int e) {
    int i = blockIdx.x * 256 + threadIdx.x;
    if (i < e) {
        int p = atomicAdd(&nxt[dst[i]], 1);
        ssrc[p] = src[i];
    }
}

// ---------------- agg0: hs[v] = (sum_{u->v} h0[u]) / deg[v]  (fp8 in, fp8 out) ----------------
// 16-lane group per node; lane loads uint4 (16 B); 8 lanes cover a row; 8 edges in flight/group

__global__ __launch_bounds__(256)
void k_agg0(const uint4* __restrict__ hg, const int* __restrict__ row_ptr,
            const int* __restrict__ ssrc, const float* __restrict__ deg,
            uint4* __restrict__ hs, int n) {
    const int tid = threadIdx.x;
    const int gid = tid >> 4, s16 = tid & 15;
    const int half = s16 >> 3, l8 = s16 & 7;
    int v = blockIdx.x * 16 + gid;
    if (v >= n) return;
    int e0 = row_ptr[v], e1 = row_ptr[v + 1];
    float acc[16];
#pragma unroll
    for (int k = 0; k < 16; k++) acc[k] = 0.f;
    for (int base = e0; base < e1; base += 8) {
        int idx[4]; float w[4];
#pragma unroll
        for (int j = 0; j < 4; j++) {
            int e = base + j * 2 + half;
            w[j] = (e < e1) ? 1.0f : 0.0f;
            idx[j] = ssrc[e < e1 ? e : e1 - 1];
        }
        uint4 x0 = hg[(size_t)idx[0] * 8 + l8];
        uint4 x1 = hg[(size_t)idx[1] * 8 + l8];
        uint4 x2 = hg[(size_t)idx[2] * 8 + l8];
        uint4 x3 = hg[(size_t)idx[3] * 8 + l8];
        float f0[16], f1[16], f2[16], f3[16];
        dec16(x0, f0); dec16(x1, f1); dec16(x2, f2); dec16(x3, f3);
#pragma unroll
        for (int k = 0; k < 16; k++) acc[k] = fmaf(w[0], f0[k], acc[k]);
#pragma unroll
        for (int k = 0; k < 16; k++) acc[k] = fmaf(w[1], f1[k], acc[k]);
#pragma unroll
        for (int k = 0; k < 16; k++) acc[k] = fmaf(w[2], f2[k], acc[k]);
#pragma unroll
        for (int k = 0; k < 16; k++) acc[k] = fmaf(w[3], f3[k], acc[k]);
    }
#pragma unroll
    for (int k = 0; k < 16; k++) acc[k] += __shfl_xor(acc[k], 8);
    if (half == 0) {
        float r = 1.0f / deg[v];
        float o[16];
#pragma unroll
        for (int k = 0; k < 16; k++) o[k] = acc[k] * r;
        hs[(size_t)v * 8 + l8] = enc16(o);
    }
}

// ---------------- GEMM0: h0_fp8[M,128] = A_f32[M,256] @ Wn + bn, fused colsum ----------------

__global__ __launch_bounds__(256)
void k_gemm0(const float* __restrict__ A, const bf16* __restrict__ WnT,
             const float* __restrict__ bias, uint4* __restrict__ Cg,
             float* __restrict__ colsum, int M) {
    constexpr int K = 256, BM = 64, BN = 128, BK = 64, LDT = BK + 8;
    __shared__ alignas(16) bf16 As[BM][LDT];
    __shared__ alignas(16) bf16 Bs[BN][LDT];
    __shared__ float cs[128];
    const int tid = threadIdx.x;
    const int wave = tid >> 6, lane = tid & 63;
    const int sub = lane & 15, rg = lane >> 4;
    const int blockRow = blockIdx.x * BM;
    if (tid < 128) cs[tid] = 0.f;

    f32x4 acc[8];
#pragma unroll
    for (int t = 0; t < 8; t++) acc[t] = (f32x4){0.f, 0.f, 0.f, 0.f};

    for (int k0 = 0; k0 < K; k0 += BK) {
#pragma unroll
        for (int it = 0; it < 4; it++) {
            int s = it * 256 + tid;
            int row = s >> 4, f4 = (s & 15) * 4;
            int grow = blockRow + row; if (grow > M - 1) grow = M - 1;
            const float4 v = *(const float4*)(A + (size_t)grow * K + k0 + f4);
            bf16x4 w = { (bf16)v.x, (bf16)v.y, (bf16)v.z, (bf16)v.w };
            *(bf16x4*)&As[row][f4] = w;
        }
        // B: straight bf16 copy from pre-transposed WnT[col][k]
#pragma unroll
        for (int it = 0; it < 4; it++) {
            int s = it * 256 + tid;
            int row = s >> 3, ch = (s & 7) * 8;
            *(bf16x8*)&Bs[row][ch] = *(const bf16x8*)(WnT + (size_t)row * 256 + k0 + ch);
        }
        __syncthreads();
#pragma unroll
        for (int kk = 0; kk < BK; kk += 32) {
            bf16x8 af = *(const bf16x8*)&As[wave * 16 + sub][kk + rg * 8];
#pragma unroll
            for (int t = 0; t < 8; t++) {
                bf16x8 bfv = *(const bf16x8*)&Bs[t * 16 + sub][kk + rg * 8];
                acc[t] = __builtin_amdgcn_mfma_f32_16x16x32_bf16(af, bfv, acc[t], 0, 0, 0);
            }
        }
        __syncthreads();
    }
    // epilogue: bias, colsum, restage tile into LDS (Bs reused) for fp8 packing
    bf16* stg = (bf16*)&Bs[0][0];       // viewed as [64][136]
    const int rbase0 = wave * 16 + rg * 4;
    float lsum[8];
#pragma unroll
    for (int t = 0; t < 8; t++) lsum[t] = 0.f;
#pragma unroll
    for (int r = 0; r < 4; r++) {
        int rowt = rbase0 + r;
        if (blockRow + rowt < M) {
#pragma unroll
            for (int t = 0; t < 8; t++) {
                int col = t * 16 + sub;
                float val = acc[t][r] + bias[col];
                lsum[t] += val;
                stg[rowt * 136 + col] = (bf16)val;
            }
        }
    }
#pragma unroll
    for (int t = 0; t < 8; t++) {
        lsum[t] += __shfl_xor(lsum[t], 16);
        lsum[t] += __shfl_xor(lsum[t], 32);
    }
    if (rg == 0) {
#pragma unroll
        for (int t = 0; t < 8; t++) atomicAdd(&cs[t * 16 + sub], lsum[t]);
    }
    __syncthreads();
    if (tid < 128) atomicAdd(&colsum[tid], cs[tid]);
#pragma unroll
    for (int it = 0; it < 2; it++) {
        int s = it * 256 + tid;      // 0..511: 64 rows x 8 quads
        int row = s >> 3, q = s & 7;
        int grow = blockRow + row;
        if (grow < M) {
            float f[16];
#pragma unroll
            for (int k = 0; k < 16; k++) f[k] = (float)stg[row * 136 + q * 16 + k];
            Cg[(size_t)grow * 8 + q] = enc16(f);
        }
    }
}

// ---------------- fused layer: A-tile = aggregation, then GEMM + leakyrelu ----------------
// agg[v] = sum_{u->v} hsin[u] + hsin[v]*deg[v];  out = leakyrelu(agg @ Wgcn + b)
// hsout[v] = fp8(out/deg[v]) when WRITE_NEXT.  hsin/hsout ping-pong (no race).

template<bool WRITE_NEXT>
__global__ __launch_bounds__(256)
void k_gemmL(const uint4* __restrict__ hsin, const int* __restrict__ row_ptr,
             const int* __restrict__ ssrc, const float* __restrict__ deg,
             const bf16* __restrict__ WgT, const float* __restrict__ bias,
             uint4* __restrict__ hsout, float* __restrict__ colsum, int M) {
    constexpr int BM = 64, BN = 128, BK = 128, LDT = BK + 8;
    __shared__ alignas(16) bf16 As[BM][LDT];
    __shared__ alignas(16) bf16 Bs[BN][LDT];
    __shared__ float cs[128];
    const int tid = threadIdx.x;
    const int wave = tid >> 6, lane = tid & 63;
    const int sub = lane & 15, rg = lane >> 4;
    const int blockRow = blockIdx.x * BM;
    if (tid < 128) cs[tid] = 0.f;

    // ---- B staging: straight bf16 copy from pre-transposed WgT[col][k] ----
#pragma unroll
    for (int it = 0; it < 8; it++) {
        int s = it * 256 + tid;
        int row = s >> 4, ch = (s & 15) * 8;
        *(bf16x8*)&Bs[row][ch] = *(const bf16x8*)(WgT + (size_t)row * 128 + ch);
    }

    // ---- A-tile via fused aggregation: 16 groups x 16 lanes, 4 rows/group ----
    // lane loads uint4 (16 B); 8 lanes cover a row; 8 edges in flight per group
    {
        const int gid = tid >> 4, s16 = tid & 15;
        const int half = s16 >> 3, l8 = s16 & 7;
        for (int i = 0; i < 4; i++) {
            int rowt = gid * 4 + i;
            int v = blockRow + rowt;
            float acc[16], fs[16];
            float d = 0.f;
#pragma unroll
            for (int k = 0; k < 16; k++) { acc[k] = 0.f; fs[k] = 0.f; }
            if (v < M) {
                int e0 = row_ptr[v], e1 = row_ptr[v + 1];
                uint4 sv = hsin[(size_t)v * 8 + l8];   // self row, issued early
                d = deg[v];
                for (int base = e0; base < e1; base += 8) {
                    int idx[4]; float w[4];
#pragma unroll
                    for (int j = 0; j < 4; j++) {
                        int e = base + j * 2 + half;
                        w[j] = (e < e1) ? 1.0f : 0.0f;
                        idx[j] = ssrc[e < e1 ? e : e1 - 1];
                    }
                    uint4 x0 = hsin[(size_t)idx[0] * 8 + l8];
                    uint4 x1 = hsin[(size_t)idx[1] * 8 + l8];
                    uint4 x2 = hsin[(size_t)idx[2] * 8 + l8];
                    uint4 x3 = hsin[(size_t)idx[3] * 8 + l8];
                    float f0[16], f1[16], f2[16], f3[16];
                    dec16(x0, f0); dec16(x1, f1); dec16(x2, f2); dec16(x3, f3);
#pragma unroll
                    for (int k = 0; k < 16; k++) acc[k] = fmaf(w[0], f0[k], acc[k]);
#pragma unroll
                    for (int k = 0; k < 16; k++) acc[k] = fmaf(w[1], f1[k], acc[k]);
#pragma unroll
                    for (int k = 0; k < 16; k++) acc[k] = fmaf(w[2], f2[k], acc[k]);
#pragma unroll
                    for (int k = 0; k < 16; k++) acc[k] = fmaf(w[3], f3[k], acc[k]);
                }
                dec16(sv, fs);
            }
            // combine halves (lanes differing in bit 3 hold the other edge of the pair)
#pragma unroll
            for (int k = 0; k < 16; k++) acc[k] += __shfl_xor(acc[k], 8);
            // self term (hsin is pre-scaled by 1/deg; *deg restores unscaled h)
#pragma unroll
            for (int k = 0; k < 16; k++) acc[k] = fmaf(fs[k], d, acc[k]);
            if (half == 0) {
                bf16x8 w0, w1;
#pragma unroll
                for (int k = 0; k < 8; k++) { w0[k] = (bf16)acc[k]; w1[k] = (bf16)acc[k + 8]; }
                *(bf16x8*)&As[rowt][l8 * 16] = w0;
                *(bf16x8*)&As[rowt][l8 * 16 + 8] = w1;
            }
        }
    }
    __syncthreads();

    // ---- MFMA ----
    f32x4 acc[8];
#pragma unroll
    for (int t = 0; t < 8; t++) acc[t] = (f32x4){0.f, 0.f, 0.f, 0.f};
#pragma unroll
    for (int kk = 0; kk < BK; kk += 32) {
        bf16x8 af = *(const bf16x8*)&As[wave * 16 + sub][kk + rg * 8];
#pragma unroll
        for (int t = 0; t < 8; t++) {
            bf16x8 bfv = *(const bf16x8*)&Bs[t * 16 + sub][kk + rg * 8];
            acc[t] = __builtin_amdgcn_mfma_f32_16x16x32_bf16(af, bfv, acc[t], 0, 0, 0);
        }
    }
    __syncthreads();

    // ---- epilogue: bias + leakyrelu + colsum (+ fp8 pack of val/deg) ----
    bf16* stg = (bf16*)&Bs[0][0];       // viewed as [64][136]
    const int rbase0 = wave * 16 + rg * 4;
    float lsum[8];
#pragma unroll
    for (int t = 0; t < 8; t++) lsum[t] = 0.f;
#pragma unroll
    for (int r = 0; r < 4; r++) {
        int rowt = rbase0 + r;
        int grow = blockRow + rowt;
        if (grow < M) {
            float rd = WRITE_NEXT ? (1.0f / deg[grow]) : 0.f;
#pragma unroll
            for (int t = 0; t < 8; t++) {
                int col = t * 16 + sub;
                float val = acc[t][r] + bias[col];
                val = (val > 0.f) ? val : NEG * val;
                lsum[t] += val;
                if (WRITE_NEXT) stg[rowt * 136 + col] = (bf16)(val * rd);
            }
        }
    }
#pragma unroll
    for (int t = 0; t < 8; t++) {
        lsum[t] += __shfl_xor(lsum[t], 16);
        lsum[t] += __shfl_xor(lsum[t], 32);
    }
    if (rg == 0) {
#pragma unroll
        for (int t = 0; t < 8; t++) atomicAdd(&cs[t * 16 + sub], lsum[t]);
    }
    __syncthreads();
    if (tid < 128) atomicAdd(&colsum[tid], cs[tid]);
    if (WRITE_NEXT) {
#pragma unroll
        for (int it = 0; it < 2; it++) {
            int s = it * 256 + tid;      // 0..511: 64 rows x 8 quads
            int row = s >> 3, q = s & 7;
            int grow = blockRow + row;
            if (grow < M) {
                float f[16];
#pragma unroll
                for (int k = 0; k < 16; k++) f[k] = (float)stg[row * 136 + q * 16 + k];
                hsout[(size_t)grow * 8 + q] = enc16(f);
            }
        }
    }
}

// ---------------- finisher ----------------

__global__ void k_final(const float* __restrict__ colsum, const float* __restrict__ Wpred,
                        const float* __restrict__ bpred, const float* __restrict__ Wcls,
                        const float* __restrict__ bcls, float* __restrict__ out, int n) {
    __shared__ float g[512];
    __shared__ float g2[128];
    __shared__ float lg[2];
    int t = threadIdx.x;  // 128 threads
    float invn = 1.0f / (float)n;
    for (int i = t; i < 512; i += 128) g[i] = colsum[i] * invn;
    __syncthreads();
    float acc = bpred[t];
    for (int i = 0; i < 512; i++) acc += g[i] * Wpred[i * 128 + t];
    g2[t] = acc;
    __syncthreads();
    if (t < 2) {
        float l = bcls[t];
        for (int j = 0; j < 128; j++) l += g2[j] * Wcls[j * 2 + t];
        lg[t] = l;
    }
    __syncthreads();
    if (t == 0) {
        float m = fmaxf(lg[0], lg[1]);
        float e0 = expf(lg[0] - m), e1 = expf(lg[1] - m);
        float s = e0 + e1;
        out[0] = e0 / s;
        out[1] = e1 / s;
    }
}

// ---------------- launch ----------------

extern "C" void kernel_launch(void* const* d_in, const int* in_sizes, int n_in,
                              void* d_out, int out_size, void* d_ws, size_t ws_size,
                              hipStream_t stream) {
    const float* node_feat = (const float*)d_in[0];
    const float* degree = (const float*)d_in[3];
    const float* Wn     = (const float*)d_in[4];
    const float* bn     = (const float*)d_in[5];
    const float* Wgcn   = (const float*)d_in[8];
    const float* bgcn   = (const float*)d_in[9];
    const float* Wpred  = (const float*)d_in[10];
    const float* bpred  = (const float*)d_in[11];
    const float* Wcls   = (const float*)d_in[12];
    const float* bcls   = (const float*)d_in[13];
    const int*   src    = (const int*)d_in[14];
    const int*   dst    = (const int*)d_in[15];
    float* out = (float*)d_out;

    const int N = in_sizes[3];
    const int E = in_sizes[14];
    (void)n_in; (void)out_size; (void)ws_size;

    char* p = (char*)d_ws;
    auto carve = [&](size_t bytes) { char* r = p; p += (bytes + 255) & ~(size_t)255; return r; };
    uint4* h0g    = (uint4*)carve((size_t)N * H);       // fp8 h0 gather table (128 B/row)
    uint4* hsb0   = (uint4*)carve((size_t)N * H);       // fp8 pre-scaled hidden, ping
    uint4* hsb1   = (uint4*)carve((size_t)N * H);       // fp8 pre-scaled hidden, pong
    bf16*  WnT    = (bf16*)carve((size_t)256 * 128 * 2);
    bf16*  WgT    = (bf16*)carve((size_t)128 * 128 * 2);
    int*   cnt    = (int*)carve((size_t)N * 4);
    int*   row_ptr= (int*)carve((size_t)(N + 1) * 4);
    int*   nxt    = (int*)carve((size_t)N * 4);
    int*   ssrc   = (int*)carve((size_t)E * 4);
    int*   part   = (int*)carve(256 * 4);
    float* colsum = (float*)carve(512 * 4);

    const int nblk = (N + 255) / 256;
    hipMemsetAsync(cnt, 0, (size_t)N * 4, stream);
    hipMemsetAsync(colsum, 0, 512 * 4, stream);

    k_prepw<<<128, 256, 0, stream>>>(Wn, Wgcn, WnT, WgT);

    k_hist<<<(E + 255) / 256, 256, 0, stream>>>(dst, cnt, E);
    k_scan1<<<nblk, 256, 0, stream>>>(cnt, part, N);
    k_scan2<<<1, 256, 0, stream>>>(part, nblk);
    k_scan3<<<nblk, 256, 0, stream>>>(cnt, part, row_ptr, nxt, N, E);
    k_fill<<<(E + 255) / 256, 256, 0, stream>>>(src, dst, nxt, ssrc, E);

    const int gblk = (N + 63) / 64;
    const int ablk = (N + 15) / 16;

    // h0 = node_feat @ Wn + bn  (fp8 out + colsum[0:128))
    k_gemm0<<<gblk, 256, 0, stream>>>(node_feat, WnT, bn, h0g, colsum, N);
    // fusion: hsb0[v] = (sum_{u->v} h0[u]) / deg[v]
    k_agg0<<<ablk, 256, 0, stream>>>(h0g, row_ptr, ssrc, degree, hsb0, N);

    // fused layers: (gather+self) -> gemm -> leakyrelu -> colsum (+ next hs, ping-pong)
    k_gemmL<true ><<<gblk, 256, 0, stream>>>(hsb0, row_ptr, ssrc, degree, WgT, bgcn, hsb1, colsum + 1 * H, N);
    k_gemmL<true ><<<gblk, 256, 0, stream>>>(hsb1, row_ptr, ssrc, degree, WgT, bgcn, hsb0, colsum + 2 * H, N);
    k_gemmL<false><<<gblk, 256, 0, stream>>>(hsb0, row_ptr, ssrc, degree, WgT, bgcn, hsb1, colsum + 3 * H, N);

    k_final<<<1, 128, 0, stream>>>(colsum, Wpred, bpred, Wcls, bcls, out, N);
}

// Round 10
// 583.941 us; speedup vs baseline: 1.0853x; 1.0190x over previous
//
#include <hip/hip_runtime.h>
#include <hip/hip_bf16.h>

#define H 128
#define NEG 0.01f

typedef __bf16 bf16;
typedef bf16 bf16x4 __attribute__((ext_vector_type(4)));
typedef bf16 bf16x8 __attribute__((ext_vector_type(8)));
typedef float f32x4 __attribute__((ext_vector_type(4)));
typedef float f32x2 __attribute__((ext_vector_type(2)));
typedef unsigned int u32;

// ---- fp8 e4m3 (OCP on gfx950) pack/unpack: 16 elems <-> 16 bytes (uint4) ----
__device__ __forceinline__ void dec16(uint4 p, float f[16]) {
    f32x2 a0 = __builtin_amdgcn_cvt_pk_f32_fp8(p.x, false);
    f32x2 a1 = __builtin_amdgcn_cvt_pk_f32_fp8(p.x, true);
    f32x2 b0 = __builtin_amdgcn_cvt_pk_f32_fp8(p.y, false);
    f32x2 b1 = __builtin_amdgcn_cvt_pk_f32_fp8(p.y, true);
    f32x2 c0 = __builtin_amdgcn_cvt_pk_f32_fp8(p.z, false);
    f32x2 c1 = __builtin_amdgcn_cvt_pk_f32_fp8(p.z, true);
    f32x2 d0 = __builtin_amdgcn_cvt_pk_f32_fp8(p.w, false);
    f32x2 d1 = __builtin_amdgcn_cvt_pk_f32_fp8(p.w, true);
    f[0]=a0[0];  f[1]=a0[1];  f[2]=a1[0];  f[3]=a1[1];
    f[4]=b0[0];  f[5]=b0[1];  f[6]=b1[0];  f[7]=b1[1];
    f[8]=c0[0];  f[9]=c0[1];  f[10]=c1[0]; f[11]=c1[1];
    f[12]=d0[0]; f[13]=d0[1]; f[14]=d1[0]; f[15]=d1[1];
}
__device__ __forceinline__ uint4 enc16(const float f[16]) {
    int a = 0, b = 0, c = 0, d = 0;
    a = __builtin_amdgcn_cvt_pk_fp8_f32(f[0],  f[1],  a, false);
    a = __builtin_amdgcn_cvt_pk_fp8_f32(f[2],  f[3],  a, true);
    b = __builtin_amdgcn_cvt_pk_fp8_f32(f[4],  f[5],  b, false);
    b = __builtin_amdgcn_cvt_pk_fp8_f32(f[6],  f[7],  b, true);
    c = __builtin_amdgcn_cvt_pk_fp8_f32(f[8],  f[9],  c, false);
    c = __builtin_amdgcn_cvt_pk_fp8_f32(f[10], f[11], c, true);
    d = __builtin_amdgcn_cvt_pk_fp8_f32(f[12], f[13], d, false);
    d = __builtin_amdgcn_cvt_pk_fp8_f32(f[14], f[15], d, true);
    uint4 r; r.x = (u32)a; r.y = (u32)b; r.z = (u32)c; r.w = (u32)d; return r;
}

// ---- edge-batch helpers: 16-lane group, 2 halves x 4 loads = 8 edges/batch ----
struct Batch { uint4 x[4]; float w[4]; };

__device__ __forceinline__ void load_batch(const uint4* __restrict__ tab,
                                           const int* __restrict__ ssrc,
                                           int base, int e1, int half, int l8, Batch& B) {
#pragma unroll
    for (int j = 0; j < 4; j++) {
        int e = base + j * 2 + half;
        B.w[j] = (e < e1) ? 1.0f : 0.0f;
        int id = ssrc[e < e1 ? e : e1 - 1];
        B.x[j] = tab[(size_t)id * 8 + l8];
    }
}

__device__ __forceinline__ void consume_batch(const Batch& B, float acc[16]) {
#pragma unroll
    for (int j = 0; j < 4; j++) {
        float f[16];
        dec16(B.x[j], f);
#pragma unroll
        for (int k = 0; k < 16; k++) acc[k] = fmaf(B.w[j], f[k], acc[k]);
    }
}

// ---------------- setup: in-degree histogram + weight pre-transpose (fused) ----------------

__global__ void k_setup(const int* __restrict__ dst, int* __restrict__ cnt, int e,
                        const float* __restrict__ Wn, const float* __restrict__ Wg,
                        bf16* __restrict__ WnT, bf16* __restrict__ WgT) {
    int i = blockIdx.x * 256 + threadIdx.x;
    if (i < e) atomicAdd(&cnt[dst[i]], 1);
    if (i < 256 * 128) {            // WnT[n][k] = Wn[k][n], K=256, Ncol=128
        int n = i >> 8, k = i & 255;
        WnT[i] = (bf16)Wn[k * 128 + n];
    }
    if (i < 128 * 128) {            // WgT[n][k] = Wg[k][n], 128x128
        int n = i >> 7, k = i & 127;
        WgT[i] = (bf16)Wg[k * 128 + n];
    }
}

// ---------------- CSR build ----------------

// per-block sums of cnt (raw, NOT pre-scanned)
__global__ void k_scan1(const int* __restrict__ cnt, int* __restrict__ part, int n) {
    __shared__ int sh[256];
    int i = blockIdx.x * 256 + threadIdx.x;
    sh[threadIdx.x] = (i < n) ? cnt[i] : 0;
    __syncthreads();
    for (int off = 128; off > 0; off >>= 1) {
        if (threadIdx.x < off) sh[threadIdx.x] += sh[threadIdx.x + off];
        __syncthreads();
    }
    if (threadIdx.x == 0) part[blockIdx.x] = sh[0];
}

// fused: block-exclusive offset (strided sum of part[0..blockIdx.x) + tree reduce)
// + per-element scan. Replaces old scan2+scan3; robust for any nblk.
__global__ void k_scan23(const int* __restrict__ cnt, const int* __restrict__ part,
                         int* __restrict__ row_ptr, int* __restrict__ nxt, int n, int e) {
    __shared__ int red[256];
    __shared__ int sh[256];
    int t = threadIdx.x;
    int i = blockIdx.x * 256 + t;
    // sum of partials strictly before this block
    int s = 0;
    for (int j = t; j < blockIdx.x; j += 256) s += part[j];
    red[t] = s;
    sh[t] = (i < n) ? cnt[i] : 0;
    __syncthreads();
    for (int off = 128; off > 0; off >>= 1) {
        if (t < off) red[t] += red[t + off];
        __syncthreads();
    }
    int blockExcl = red[0];
    // inclusive scan of this block's counts
    for (int off = 1; off < 256; off <<= 1) {
        int v = (t >= off) ? sh[t - off] : 0;
        __syncthreads();
        sh[t] += v;
        __syncthreads();
    }
    int excl = blockExcl + ((t == 0) ? 0 : sh[t - 1]);
    if (i < n) { row_ptr[i] = excl; nxt[i] = excl; }
    if (i == 0) row_ptr[n] = e;
}

__global__ void k_fill(const int* __restrict__ src, const int* __restrict__ dst,
                       int* __restrict__ nxt, int* __restrict__ ssrc, int e) {
    int i = blockIdx.x * 256 + threadIdx.x;
    if (i < e) {
        int p = atomicAdd(&nxt[dst[i]], 1);
        ssrc[p] = src[i];
    }
}

// ---------------- agg0: hs[v] = (sum_{u->v} h0[u]) / deg[v]  (fp8 in, fp8 out) ----------------
// 16-lane group/node; reg-double-buffered batches: 8 loads in flight per group

__global__ __launch_bounds__(256)
void k_agg0(const uint4* __restrict__ hg, const int* __restrict__ row_ptr,
            const int* __restrict__ ssrc, const float* __restrict__ deg,
            uint4* __restrict__ hs, int n) {
    const int tid = threadIdx.x;
    const int gid = tid >> 4, s16 = tid & 15;
    const int half = s16 >> 3, l8 = s16 & 7;
    int v = blockIdx.x * 16 + gid;
    if (v >= n) return;
    int e0 = row_ptr[v], e1 = row_ptr[v + 1];
    float rdeg = 1.0f / deg[v];
    float acc[16];
#pragma unroll
    for (int k = 0; k < 16; k++) acc[k] = 0.f;
    int nbatch = (e1 - e0 + 7) >> 3;
    Batch cur, nxt;
    if (nbatch > 0) load_batch(hg, ssrc, e0, e1, half, l8, cur);
    for (int b = 0; b < nbatch; b++) {
        bool more = (b + 1 < nbatch);
        if (more) load_batch(hg, ssrc, e0 + (b + 1) * 8, e1, half, l8, nxt);
        consume_batch(cur, acc);
        if (more) cur = nxt;
    }
#pragma unroll
    for (int k = 0; k < 16; k++) acc[k] += __shfl_xor(acc[k], 8);
    if (half == 0) {
        float o[16];
#pragma unroll
        for (int k = 0; k < 16; k++) o[k] = acc[k] * rdeg;
        hs[(size_t)v * 8 + l8] = enc16(o);
    }
}

// ---------------- GEMM0: h0_fp8[M,128] = A_f32[M,256] @ Wn + bn, fused colsum ----------------

__global__ __launch_bounds__(256)
void k_gemm0(const float* __restrict__ A, const bf16* __restrict__ WnT,
             const float* __restrict__ bias, uint4* __restrict__ Cg,
             float* __restrict__ colsum, int M) {
    constexpr int K = 256, BM = 64, BN = 128, BK = 64, LDT = BK + 8;
    __shared__ alignas(16) bf16 As[BM][LDT];
    __shared__ alignas(16) bf16 Bs[BN][LDT];
    __shared__ float cs[128];
    const int tid = threadIdx.x;
    const int wave = tid >> 6, lane = tid & 63;
    const int sub = lane & 15, rg = lane >> 4;
    const int blockRow = blockIdx.x * BM;
    if (tid < 128) cs[tid] = 0.f;

    f32x4 acc[8];
#pragma unroll
    for (int t = 0; t < 8; t++) acc[t] = (f32x4){0.f, 0.f, 0.f, 0.f};

    for (int k0 = 0; k0 < K; k0 += BK) {
#pragma unroll
        for (int it = 0; it < 4; it++) {
            int s = it * 256 + tid;
            int row = s >> 4, f4 = (s & 15) * 4;
            int grow = blockRow + row; if (grow > M - 1) grow = M - 1;
            const float4 v = *(const float4*)(A + (size_t)grow * K + k0 + f4);
            bf16x4 w = { (bf16)v.x, (bf16)v.y, (bf16)v.z, (bf16)v.w };
            *(bf16x4*)&As[row][f4] = w;
        }
        // B: straight bf16 copy from pre-transposed WnT[col][k]
#pragma unroll
        for (int it = 0; it < 4; it++) {
            int s = it * 256 + tid;
            int row = s >> 3, ch = (s & 7) * 8;
            *(bf16x8*)&Bs[row][ch] = *(const bf16x8*)(WnT + (size_t)row * 256 + k0 + ch);
        }
        __syncthreads();
#pragma unroll
        for (int kk = 0; kk < BK; kk += 32) {
            bf16x8 af = *(const bf16x8*)&As[wave * 16 + sub][kk + rg * 8];
#pragma unroll
            for (int t = 0; t < 8; t++) {
                bf16x8 bfv = *(const bf16x8*)&Bs[t * 16 + sub][kk + rg * 8];
                acc[t] = __builtin_amdgcn_mfma_f32_16x16x32_bf16(af, bfv, acc[t], 0, 0, 0);
            }
        }
        __syncthreads();
    }
    // epilogue: bias, colsum, restage tile into LDS (Bs reused) for fp8 packing
    bf16* stg = (bf16*)&Bs[0][0];       // viewed as [64][136]
    const int rbase0 = wave * 16 + rg * 4;
    float lsum[8];
#pragma unroll
    for (int t = 0; t < 8; t++) lsum[t] = 0.f;
#pragma unroll
    for (int r = 0; r < 4; r++) {
        int rowt = rbase0 + r;
        if (blockRow + rowt < M) {
#pragma unroll
            for (int t = 0; t < 8; t++) {
                int col = t * 16 + sub;
                float val = acc[t][r] + bias[col];
                lsum[t] += val;
                stg[rowt * 136 + col] = (bf16)val;
            }
        }
    }
#pragma unroll
    for (int t = 0; t < 8; t++) {
        lsum[t] += __shfl_xor(lsum[t], 16);
        lsum[t] += __shfl_xor(lsum[t], 32);
    }
    if (rg == 0) {
#pragma unroll
        for (int t = 0; t < 8; t++) atomicAdd(&cs[t * 16 + sub], lsum[t]);
    }
    __syncthreads();
    if (tid < 128) atomicAdd(&colsum[tid], cs[tid]);
#pragma unroll
    for (int it = 0; it < 2; it++) {
        int s = it * 256 + tid;      // 0..511: 64 rows x 8 quads
        int row = s >> 3, q = s & 7;
        int grow = blockRow + row;
        if (grow < M) {
            float f[16];
#pragma unroll
            for (int k = 0; k < 16; k++) f[k] = (float)stg[row * 136 + q * 16 + k];
            Cg[(size_t)grow * 8 + q] = enc16(f);
        }
    }
}

// ---------------- fused layer: A-tile = aggregation, then GEMM + leakyrelu ----------------
// agg[v] = sum_{u->v} hsin[u] + hsin[v]*deg[v];  out = leakyrelu(agg @ Wgcn + b)
// hsout[v] = fp8(out/deg[v]) when WRITE_NEXT.  hsin/hsout ping-pong (no race).

template<bool WRITE_NEXT>
__global__ __launch_bounds__(256)
void k_gemmL(const uint4* __restrict__ hsin, const int* __restrict__ row_ptr,
             const int* __restrict__ ssrc, const float* __restrict__ deg,
             const bf16* __restrict__ WgT, const float* __restrict__ bias,
             uint4* __restrict__ hsout, float* __restrict__ colsum, int M) {
    constexpr int BM = 64, BN = 128, BK = 128, LDT = BK + 8;
    __shared__ alignas(16) bf16 As[BM][LDT];
    __shared__ alignas(16) bf16 Bs[BN][LDT];
    __shared__ float cs[128];
    const int tid = threadIdx.x;
    const int wave = tid >> 6, lane = tid & 63;
    const int sub = lane & 15, rg = lane >> 4;
    const int blockRow = blockIdx.x * BM;
    if (tid < 128) cs[tid] = 0.f;

    // ---- B staging: straight bf16 copy from pre-transposed WgT[col][k] ----
#pragma unroll
    for (int it = 0; it < 8; it++) {
        int s = it * 256 + tid;
        int row = s >> 4, ch = (s & 15) * 8;
        *(bf16x8*)&Bs[row][ch] = *(const bf16x8*)(WgT + (size_t)row * 128 + ch);
    }

    // ---- A-tile via fused aggregation: 16 groups x 16 lanes, 4 rows/group ----
    // reg-double-buffered batches: 8 edge-loads in flight per group
    {
        const int gid = tid >> 4, s16 = tid & 15;
        const int half = s16 >> 3, l8 = s16 & 7;
        for (int i = 0; i < 4; i++) {
            int rowt = gid * 4 + i;
            int v = blockRow + rowt;
            float acc[16], fs[16];
            float d = 0.f;
#pragma unroll
            for (int k = 0; k < 16; k++) { acc[k] = 0.f; fs[k] = 0.f; }
            if (v < M) {
                int e0 = row_ptr[v], e1 = row_ptr[v + 1];
                uint4 sv = hsin[(size_t)v * 8 + l8];   // self row, issued early
                d = deg[v];
                int nbatch = (e1 - e0 + 7) >> 3;
                Batch cur, nxt;
                if (nbatch > 0) load_batch(hsin, ssrc, e0, e1, half, l8, cur);
                for (int b = 0; b < nbatch; b++) {
                    bool more = (b + 1 < nbatch);
                    if (more) load_batch(hsin, ssrc, e0 + (b + 1) * 8, e1, half, l8, nxt);
                    consume_batch(cur, acc);
                    if (more) cur = nxt;
                }
                dec16(sv, fs);
            }
            // combine halves (lanes differing in bit 3 hold the other edge of the pair)
#pragma unroll
            for (int k = 0; k < 16; k++) acc[k] += __shfl_xor(acc[k], 8);
            // self term (hsin is pre-scaled by 1/deg; *deg restores unscaled h)
#pragma unroll
            for (int k = 0; k < 16; k++) acc[k] = fmaf(fs[k], d, acc[k]);
            if (half == 0) {
                bf16x8 w0, w1;
#pragma unroll
                for (int k = 0; k < 8; k++) { w0[k] = (bf16)acc[k]; w1[k] = (bf16)acc[k + 8]; }
                *(bf16x8*)&As[rowt][l8 * 16] = w0;
                *(bf16x8*)&As[rowt][l8 * 16 + 8] = w1;
            }
        }
    }
    __syncthreads();

    // ---- MFMA ----
    f32x4 acc[8];
#pragma unroll
    for (int t = 0; t < 8; t++) acc[t] = (f32x4){0.f, 0.f, 0.f, 0.f};
#pragma unroll
    for (int kk = 0; kk < BK; kk += 32) {
        bf16x8 af = *(const bf16x8*)&As[wave * 16 + sub][kk + rg * 8];
#pragma unroll
        for (int t = 0; t < 8; t++) {
            bf16x8 bfv = *(const bf16x8*)&Bs[t * 16 + sub][kk + rg * 8];
            acc[t] = __builtin_amdgcn_mfma_f32_16x16x32_bf16(af, bfv, acc[t], 0, 0, 0);
        }
    }
    __syncthreads();

    // ---- epilogue: bias + leakyrelu + colsum (+ fp8 pack of val/deg) ----
    bf16* stg = (bf16*)&Bs[0][0];       // viewed as [64][136]
    const int rbase0 = wave * 16 + rg * 4;
    float lsum[8];
#pragma unroll
    for (int t = 0; t < 8; t++) lsum[t] = 0.f;
#pragma unroll
    for (int r = 0; r < 4; r++) {
        int rowt = rbase0 + r;
        int grow = blockRow + rowt;
        if (grow < M) {
            float rd = WRITE_NEXT ? (1.0f / deg[grow]) : 0.f;
#pragma unroll
            for (int t = 0; t < 8; t++) {
                int col = t * 16 + sub;
                float val = acc[t][r] + bias[col];
                val = (val > 0.f) ? val : NEG * val;
                lsum[t] += val;
                if (WRITE_NEXT) stg[rowt * 136 + col] = (bf16)(val * rd);
            }
        }
    }
#pragma unroll
    for (int t = 0; t < 8; t++) {
        lsum[t] += __shfl_xor(lsum[t], 16);
        lsum[t] += __shfl_xor(lsum[t], 32);
    }
    if (rg == 0) {
#pragma unroll
        for (int t = 0; t < 8; t++) atomicAdd(&cs[t * 16 + sub], lsum[t]);
    }
    __syncthreads();
    if (tid < 128) atomicAdd(&colsum[tid], cs[tid]);
    if (WRITE_NEXT) {
#pragma unroll
        for (int it = 0; it < 2; it++) {
            int s = it * 256 + tid;      // 0..511: 64 rows x 8 quads
            int row = s >> 3, q = s & 7;
            int grow = blockRow + row;
            if (grow < M) {
                float f[16];
#pragma unroll
                for (int k = 0; k < 16; k++) f[k] = (float)stg[row * 136 + q * 16 + k];
                hsout[(size_t)grow * 8 + q] = enc16(f);
            }
        }
    }
}

// ---------------- finisher ----------------

__global__ void k_final(const float* __restrict__ colsum, const float* __restrict__ Wpred,
                        const float* __restrict__ bpred, const float* __restrict__ Wcls,
                        const float* __restrict__ bcls, float* __restrict__ out, int n) {
    __shared__ float g[512];
    __shared__ float g2[128];
    __shared__ float lg[2];
    int t = threadIdx.x;  // 128 threads
    float invn = 1.0f / (float)n;
    for (int i = t; i < 512; i += 128) g[i] = colsum[i] * invn;
    __syncthreads();
    float acc = bpred[t];
    for (int i = 0; i < 512; i++) acc += g[i] * Wpred[i * 128 + t];
    g2[t] = acc;
    __syncthreads();
    if (t < 2) {
        float l = bcls[t];
        for (int j = 0; j < 128; j++) l += g2[j] * Wcls[j * 2 + t];
        lg[t] = l;
    }
    __syncthreads();
    if (t == 0) {
        float m = fmaxf(lg[0], lg[1]);
        float e0 = expf(lg[0] - m), e1 = expf(lg[1] - m);
        float s = e0 + e1;
        out[0] = e0 / s;
        out[1] = e1 / s;
    }
}

// ---------------- launch ----------------

extern "C" void kernel_launch(void* const* d_in, const int* in_sizes, int n_in,
                              void* d_out, int out_size, void* d_ws, size_t ws_size,
                              hipStream_t stream) {
    const float* node_feat = (const float*)d_in[0];
    const float* degree = (const float*)d_in[3];
    const float* Wn     = (const float*)d_in[4];
    const float* bn     = (const float*)d_in[5];
    const float* Wgcn   = (const float*)d_in[8];
    const float* bgcn   = (const float*)d_in[9];
    const float* Wpred  = (const float*)d_in[10];
    const float* bpred  = (const float*)d_in[11];
    const float* Wcls   = (const float*)d_in[12];
    const float* bcls   = (const float*)d_in[13];
    const int*   src    = (const int*)d_in[14];
    const int*   dst    = (const int*)d_in[15];
    float* out = (float*)d_out;

    const int N = in_sizes[3];
    const int E = in_sizes[14];
    (void)n_in; (void)out_size; (void)ws_size;

    char* p = (char*)d_ws;
    auto carve = [&](size_t bytes) { char* r = p; p += (bytes + 255) & ~(size_t)255; return r; };
    // cnt + colsum carved adjacently -> single memset covers both
    int*   cnt    = (int*)carve((size_t)N * 4);
    float* colsum = (float*)carve(512 * 4);
    uint4* h0g    = (uint4*)carve((size_t)N * H);       // fp8 h0 gather table (128 B/row)
    uint4* hsb0   = (uint4*)carve((size_t)N * H);       // fp8 pre-scaled hidden, ping
    uint4* hsb1   = (uint4*)carve((size_t)N * H);       // fp8 pre-scaled hidden, pong
    bf16*  WnT    = (bf16*)carve((size_t)256 * 128 * 2);
    bf16*  WgT    = (bf16*)carve((size_t)128 * 128 * 2);
    int*   row_ptr= (int*)carve((size_t)(N + 1) * 4);
    int*   nxt    = (int*)carve((size_t)N * 4);
    int*   ssrc   = (int*)carve((size_t)E * 4);
    int*   part   = (int*)carve(256 * 4);

    const int nblk = (N + 255) / 256;
    // zero cnt..colsum in one fill (contiguous carve region)
    hipMemsetAsync(cnt, 0, (size_t)((char*)(colsum + 512) - (char*)cnt), stream);

    // fused: in-degree histogram + weight pre-transpose
    k_setup<<<(E + 255) / 256, 256, 0, stream>>>(dst, cnt, E, Wn, Wgcn, WnT, WgT);
    k_scan1<<<nblk, 256, 0, stream>>>(cnt, part, N);
    k_scan23<<<nblk, 256, 0, stream>>>(cnt, part, row_ptr, nxt, N, E);
    k_fill<<<(E + 255) / 256, 256, 0, stream>>>(src, dst, nxt, ssrc, E);

    const int gblk = (N + 63) / 64;
    const int ablk = (N + 15) / 16;

    // h0 = node_feat @ Wn + bn  (fp8 out + colsum[0:128))
    k_gemm0<<<gblk, 256, 0, stream>>>(node_feat, WnT, bn, h0g, colsum, N);
    // fusion: hsb0[v] = (sum_{u->v} h0[u]) / deg[v]
    k_agg0<<<ablk, 256, 0, stream>>>(h0g, row_ptr, ssrc, degree, hsb0, N);

    // fused layers: (gather+self) -> gemm -> leakyrelu -> colsum (+ next hs, ping-pong)
    k_gemmL<true ><<<gblk, 256, 0, stream>>>(hsb0, row_ptr, ssrc, degree, WgT, bgcn, hsb1, colsum + 1 * H, N);
    k_gemmL<true ><<<gblk, 256, 0, stream>>>(hsb1, row_ptr, ssrc, degree, WgT, bgcn, hsb0, colsum + 2 * H, N);
    k_gemmL<false><<<gblk, 256, 0, stream>>>(hsb0, row_ptr, ssrc, degree, WgT, bgcn, hsb1, colsum + 3 * H, N);

    k_final<<<1, 128, 0, stream>>>(colsum, Wpred, bpred, Wcls, bcls, out, N);
}

// Round 14
// 574.033 us; speedup vs baseline: 1.1040x; 1.0173x over previous
//
#include <hip/hip_runtime.h>
#include <hip/hip_bf16.h>

#define H 128
#define NEG 0.01f

typedef __bf16 bf16;
typedef bf16 bf16x4 __attribute__((ext_vector_type(4)));
typedef bf16 bf16x8 __attribute__((ext_vector_type(8)));
typedef float f32x4 __attribute__((ext_vector_type(4)));
typedef float f32x2 __attribute__((ext_vector_type(2)));
typedef unsigned int u32;

// ---- fp8 e4m3 (OCP on gfx950) pack/unpack: 16 elems <-> 16 bytes (uint4) ----
__device__ __forceinline__ void dec16(uint4 p, float f[16]) {
    f32x2 a0 = __builtin_amdgcn_cvt_pk_f32_fp8(p.x, false);
    f32x2 a1 = __builtin_amdgcn_cvt_pk_f32_fp8(p.x, true);
    f32x2 b0 = __builtin_amdgcn_cvt_pk_f32_fp8(p.y, false);
    f32x2 b1 = __builtin_amdgcn_cvt_pk_f32_fp8(p.y, true);
    f32x2 c0 = __builtin_amdgcn_cvt_pk_f32_fp8(p.z, false);
    f32x2 c1 = __builtin_amdgcn_cvt_pk_f32_fp8(p.z, true);
    f32x2 d0 = __builtin_amdgcn_cvt_pk_f32_fp8(p.w, false);
    f32x2 d1 = __builtin_amdgcn_cvt_pk_f32_fp8(p.w, true);
    f[0]=a0[0];  f[1]=a0[1];  f[2]=a1[0];  f[3]=a1[1];
    f[4]=b0[0];  f[5]=b0[1];  f[6]=b1[0];  f[7]=b1[1];
    f[8]=c0[0];  f[9]=c0[1];  f[10]=c1[0]; f[11]=c1[1];
    f[12]=d0[0]; f[13]=d0[1]; f[14]=d1[0]; f[15]=d1[1];
}
__device__ __forceinline__ uint4 enc16(const float f[16]) {
    int a = 0, b = 0, c = 0, d = 0;
    a = __builtin_amdgcn_cvt_pk_fp8_f32(f[0],  f[1],  a, false);
    a = __builtin_amdgcn_cvt_pk_fp8_f32(f[2],  f[3],  a, true);
    b = __builtin_amdgcn_cvt_pk_fp8_f32(f[4],  f[5],  b, false);
    b = __builtin_amdgcn_cvt_pk_fp8_f32(f[6],  f[7],  b, true);
    c = __builtin_amdgcn_cvt_pk_fp8_f32(f[8],  f[9],  c, false);
    c = __builtin_amdgcn_cvt_pk_fp8_f32(f[10], f[11], c, true);
    d = __builtin_amdgcn_cvt_pk_fp8_f32(f[12], f[13], d, false);
    d = __builtin_amdgcn_cvt_pk_fp8_f32(f[14], f[15], d, true);
    uint4 r; r.x = (u32)a; r.y = (u32)b; r.z = (u32)c; r.w = (u32)d; return r;
}

// ---- edge-batch helpers: 16-lane group, 2 halves x 4 loads = 8 edges/batch ----
struct Batch { uint4 x[4]; float w[4]; };

__device__ __forceinline__ void load_batch(const uint4* __restrict__ tab,
                                           const int* __restrict__ ssrc,
                                           int base, int e1, int half, int l8, Batch& B) {
#pragma unroll
    for (int j = 0; j < 4; j++) {
        int e = base + j * 2 + half;
        B.w[j] = (e < e1) ? 1.0f : 0.0f;
        int id = ssrc[e < e1 ? e : e1 - 1];
        B.x[j] = tab[(size_t)id * 8 + l8];
    }
}

__device__ __forceinline__ void consume_batch(const Batch& B, float acc[16]) {
#pragma unroll
    for (int j = 0; j < 4; j++) {
        float f[16];
        dec16(B.x[j], f);
#pragma unroll
        for (int k = 0; k < 16; k++) acc[k] = fmaf(B.w[j], f[k], acc[k]);
    }
}

// ---------------- setup: in-degree histogram + weight pre-transpose (fused) ----------------

__global__ void k_setup(const int* __restrict__ dst, int* __restrict__ cnt, int e,
                        const float* __restrict__ Wn, const float* __restrict__ Wg,
                        bf16* __restrict__ WnT, bf16* __restrict__ WgT) {
    int i = blockIdx.x * 256 + threadIdx.x;
    if (i < e) atomicAdd(&cnt[dst[i]], 1);
    if (i < 256 * 128) {            // WnT[n][k] = Wn[k][n], K=256, Ncol=128
        int n = i >> 8, k = i & 255;
        WnT[i] = (bf16)Wn[k * 128 + n];
    }
    if (i < 128 * 128) {            // WgT[n][k] = Wg[k][n], 128x128
        int n = i >> 7, k = i & 127;
        WgT[i] = (bf16)Wg[k * 128 + n];
    }
}

// ---------------- CSR build ----------------

// per-block sums of cnt (raw, NOT pre-scanned)
__global__ void k_scan1(const int* __restrict__ cnt, int* __restrict__ part, int n) {
    __shared__ int sh[256];
    int i = blockIdx.x * 256 + threadIdx.x;
    sh[threadIdx.x] = (i < n) ? cnt[i] : 0;
    __syncthreads();
    for (int off = 128; off > 0; off >>= 1) {
        if (threadIdx.x < off) sh[threadIdx.x] += sh[threadIdx.x + off];
        __syncthreads();
    }
    if (threadIdx.x == 0) part[blockIdx.x] = sh[0];
}

// fused: block-exclusive offset (strided sum of part[0..blockIdx.x) + tree reduce)
// + per-element scan. Robust for any nblk.
__global__ void k_scan23(const int* __restrict__ cnt, const int* __restrict__ part,
                         int* __restrict__ row_ptr, int* __restrict__ nxt, int n, int e) {
    __shared__ int red[256];
    __shared__ int sh[256];
    int t = threadIdx.x;
    int i = blockIdx.x * 256 + t;
    // sum of partials strictly before this block
    int s = 0;
    for (int j = t; j < blockIdx.x; j += 256) s += part[j];
    red[t] = s;
    sh[t] = (i < n) ? cnt[i] : 0;
    __syncthreads();
    for (int off = 128; off > 0; off >>= 1) {
        if (t < off) red[t] += red[t + off];
        __syncthreads();
    }
    int blockExcl = red[0];
    // inclusive scan of this block's counts
    for (int off = 1; off < 256; off <<= 1) {
        int v = (t >= off) ? sh[t - off] : 0;
        __syncthreads();
        sh[t] += v;
        __syncthreads();
    }
    int excl = blockExcl + ((t == 0) ? 0 : sh[t - 1]);
    if (i < n) { row_ptr[i] = excl; nxt[i] = excl; }
    if (i == 0) row_ptr[n] = e;
}

// ---------------- fused: bucket-fill (blocks [0,fillBlks)) + GEMM0 (rest) ----------------
// Both parts' inputs are ready after k_scan23: fill needs nxt, gemm0 needs WnT.
// No inter-block communication; fill blocks never touch LDS/syncthreads.

__global__ __launch_bounds__(256)
void k_fillgemm0(const int* __restrict__ src, const int* __restrict__ dst,
                 int* __restrict__ nxt, int* __restrict__ ssrc, int e, int fillBlks,
                 const float* __restrict__ A, const bf16* __restrict__ WnT,
                 const float* __restrict__ bias, uint4* __restrict__ Cg,
                 float* __restrict__ colsum, int M) {
    constexpr int K = 256, BM = 64, BN = 128, BK = 64, LDT = BK + 8;
    __shared__ alignas(16) bf16 As[BM][LDT];
    __shared__ alignas(16) bf16 Bs[BN][LDT];
    __shared__ float cs[128];
    const int tid = threadIdx.x;

    if ((int)blockIdx.x < fillBlks) {
        int i = blockIdx.x * 256 + tid;
        if (i < e) {
            int p = atomicAdd(&nxt[dst[i]], 1);
            ssrc[p] = src[i];
        }
        return;
    }

    const int wave = tid >> 6, lane = tid & 63;
    const int sub = lane & 15, rg = lane >> 4;
    const int blockRow = (blockIdx.x - fillBlks) * BM;
    if (tid < 128) cs[tid] = 0.f;

    f32x4 acc[8];
#pragma unroll
    for (int t = 0; t < 8; t++) acc[t] = (f32x4){0.f, 0.f, 0.f, 0.f};

    for (int k0 = 0; k0 < K; k0 += BK) {
#pragma unroll
        for (int it = 0; it < 4; it++) {
            int s = it * 256 + tid;
            int row = s >> 4, f4 = (s & 15) * 4;
            int grow = blockRow + row; if (grow > M - 1) grow = M - 1;
            const float4 v = *(const float4*)(A + (size_t)grow * K + k0 + f4);
            bf16x4 w = { (bf16)v.x, (bf16)v.y, (bf16)v.z, (bf16)v.w };
            *(bf16x4*)&As[row][f4] = w;
        }
        // B: straight bf16 copy from pre-transposed WnT[col][k]
#pragma unroll
        for (int it = 0; it < 4; it++) {
            int s = it * 256 + tid;
            int row = s >> 3, ch = (s & 7) * 8;
            *(bf16x8*)&Bs[row][ch] = *(const bf16x8*)(WnT + (size_t)row * 256 + k0 + ch);
        }
        __syncthreads();
#pragma unroll
        for (int kk = 0; kk < BK; kk += 32) {
            bf16x8 af = *(const bf16x8*)&As[wave * 16 + sub][kk + rg * 8];
#pragma unroll
            for (int t = 0; t < 8; t++) {
                bf16x8 bfv = *(const bf16x8*)&Bs[t * 16 + sub][kk + rg * 8];
                acc[t] = __builtin_amdgcn_mfma_f32_16x16x32_bf16(af, bfv, acc[t], 0, 0, 0);
            }
        }
        __syncthreads();
    }
    // epilogue: bias, colsum, restage tile into LDS (Bs reused) for fp8 packing
    bf16* stg = (bf16*)&Bs[0][0];       // viewed as [64][136]
    const int rbase0 = wave * 16 + rg * 4;
    float lsum[8];
#pragma unroll
    for (int t = 0; t < 8; t++) lsum[t] = 0.f;
#pragma unroll
    for (int r = 0; r < 4; r++) {
        int rowt = rbase0 + r;
        if (blockRow + rowt < M) {
#pragma unroll
            for (int t = 0; t < 8; t++) {
                int col = t * 16 + sub;
                float val = acc[t][r] + bias[col];
                lsum[t] += val;
                stg[rowt * 136 + col] = (bf16)val;
            }
        }
    }
#pragma unroll
    for (int t = 0; t < 8; t++) {
        lsum[t] += __shfl_xor(lsum[t], 16);
        lsum[t] += __shfl_xor(lsum[t], 32);
    }
    if (rg == 0) {
#pragma unroll
        for (int t = 0; t < 8; t++) atomicAdd(&cs[t * 16 + sub], lsum[t]);
    }
    __syncthreads();
    if (tid < 128) atomicAdd(&colsum[tid], cs[tid]);
#pragma unroll
    for (int it = 0; it < 2; it++) {
        int s = it * 256 + tid;      // 0..511: 64 rows x 8 quads
        int row = s >> 3, q = s & 7;
        int grow = blockRow + row;
        if (grow < M) {
            float f[16];
#pragma unroll
            for (int k = 0; k < 16; k++) f[k] = (float)stg[row * 136 + q * 16 + k];
            Cg[(size_t)grow * 8 + q] = enc16(f);
        }
    }
}

// ---------------- agg0: hs[v] = (sum_{u->v} h0[u]) / deg[v]  (fp8 in, fp8 out) ----------------
// 16-lane group/node; reg-double-buffered batches: 8 loads in flight per group

__global__ __launch_bounds__(256)
void k_agg0(const uint4* __restrict__ hg, const int* __restrict__ row_ptr,
            const int* __restrict__ ssrc, const float* __restrict__ deg,
            uint4* __restrict__ hs, int n) {
    const int tid = threadIdx.x;
    const int gid = tid >> 4, s16 = tid & 15;
    const int half = s16 >> 3, l8 = s16 & 7;
    int v = blockIdx.x * 16 + gid;
    if (v >= n) return;
    int e0 = row_ptr[v], e1 = row_ptr[v + 1];
    float rdeg = 1.0f / deg[v];
    float acc[16];
#pragma unroll
    for (int k = 0; k < 16; k++) acc[k] = 0.f;
    int nbatch = (e1 - e0 + 7) >> 3;
    Batch cur, nxt;
    if (nbatch > 0) load_batch(hg, ssrc, e0, e1, half, l8, cur);
    for (int b = 0; b < nbatch; b++) {
        bool more = (b + 1 < nbatch);
        if (more) load_batch(hg, ssrc, e0 + (b + 1) * 8, e1, half, l8, nxt);
        consume_batch(cur, acc);
        if (more) cur = nxt;
    }
#pragma unroll
    for (int k = 0; k < 16; k++) acc[k] += __shfl_xor(acc[k], 8);
    if (half == 0) {
        float o[16];
#pragma unroll
        for (int k = 0; k < 16; k++) o[k] = acc[k] * rdeg;
        hs[(size_t)v * 8 + l8] = enc16(o);
    }
}

// ---------------- fused layer: A-tile = aggregation, then GEMM + leakyrelu ----------------
// agg[v] = sum_{u->v} hsin[u] + hsin[v]*deg[v];  out = leakyrelu(agg @ Wgcn + b)
// hsout[v] = fp8(out/deg[v]) when WRITE_NEXT.  hsin/hsout ping-pong across DISPATCHES
// (dispatch boundaries provide the cross-XCD flush/invalidate — G16; grid.sync does NOT).

template<bool WRITE_NEXT>
__global__ __launch_bounds__(256)
void k_gemmL(const uint4* __restrict__ hsin, const int* __restrict__ row_ptr,
             const int* __restrict__ ssrc, const float* __restrict__ deg,
             const bf16* __restrict__ WgT, const float* __restrict__ bias,
             uint4* __restrict__ hsout, float* __restrict__ colsum, int M) {
    constexpr int BM = 64, BN = 128, BK = 128, LDT = BK + 8;
    __shared__ alignas(16) bf16 As[BM][LDT];
    __shared__ alignas(16) bf16 Bs[BN][LDT];
    __shared__ float cs[128];
    const int tid = threadIdx.x;
    const int wave = tid >> 6, lane = tid & 63;
    const int sub = lane & 15, rg = lane >> 4;
    const int blockRow = blockIdx.x * BM;
    if (tid < 128) cs[tid] = 0.f;

    // ---- B staging: straight bf16 copy from pre-transposed WgT[col][k] ----
#pragma unroll
    for (int it = 0; it < 8; it++) {
        int s = it * 256 + tid;
        int row = s >> 4, ch = (s & 15) * 8;
        *(bf16x8*)&Bs[row][ch] = *(const bf16x8*)(WgT + (size_t)row * 128 + ch);
    }

    // ---- A-tile via fused aggregation: 16 groups x 16 lanes, 4 rows/group ----
    // reg-double-buffered batches: 8 edge-loads in flight per group
    {
        const int gid = tid >> 4, s16 = tid & 15;
        const int half = s16 >> 3, l8 = s16 & 7;
        for (int i = 0; i < 4; i++) {
            int rowt = gid * 4 + i;
            int v = blockRow + rowt;
            float acc[16], fs[16];
            float d = 0.f;
#pragma unroll
            for (int k = 0; k < 16; k++) { acc[k] = 0.f; fs[k] = 0.f; }
            if (v < M) {
                int e0 = row_ptr[v], e1 = row_ptr[v + 1];
                uint4 sv = hsin[(size_t)v * 8 + l8];   // self row, issued early
                d = deg[v];
                int nbatch = (e1 - e0 + 7) >> 3;
                Batch cur, nxt;
                if (nbatch > 0) load_batch(hsin, ssrc, e0, e1, half, l8, cur);
                for (int b = 0; b < nbatch; b++) {
                    bool more = (b + 1 < nbatch);
                    if (more) load_batch(hsin, ssrc, e0 + (b + 1) * 8, e1, half, l8, nxt);
                    consume_batch(cur, acc);
                    if (more) cur = nxt;
                }
                dec16(sv, fs);
            }
            // combine halves (lanes differing in bit 3 hold the other edge of the pair)
#pragma unroll
            for (int k = 0; k < 16; k++) acc[k] += __shfl_xor(acc[k], 8);
            // self term (hsin is pre-scaled by 1/deg; *deg restores unscaled h)
#pragma unroll
            for (int k = 0; k < 16; k++) acc[k] = fmaf(fs[k], d, acc[k]);
            if (half == 0) {
                bf16x8 w0, w1;
#pragma unroll
                for (int k = 0; k < 8; k++) { w0[k] = (bf16)acc[k]; w1[k] = (bf16)acc[k + 8]; }
                *(bf16x8*)&As[rowt][l8 * 16] = w0;
                *(bf16x8*)&As[rowt][l8 * 16 + 8] = w1;
            }
        }
    }
    __syncthreads();

    // ---- MFMA ----
    f32x4 acc[8];
#pragma unroll
    for (int t = 0; t < 8; t++) acc[t] = (f32x4){0.f, 0.f, 0.f, 0.f};
#pragma unroll
    for (int kk = 0; kk < BK; kk += 32) {
        bf16x8 af = *(const bf16x8*)&As[wave * 16 + sub][kk + rg * 8];
#pragma unroll
        for (int t = 0; t < 8; t++) {
            bf16x8 bfv = *(const bf16x8*)&Bs[t * 16 + sub][kk + rg * 8];
            acc[t] = __builtin_amdgcn_mfma_f32_16x16x32_bf16(af, bfv, acc[t], 0, 0, 0);
        }
    }
    __syncthreads();

    // ---- epilogue: bias + leakyrelu + colsum (+ fp8 pack of val/deg) ----
    bf16* stg = (bf16*)&Bs[0][0];       // viewed as [64][136]
    const int rbase0 = wave * 16 + rg * 4;
    float lsum[8];
#pragma unroll
    for (int t = 0; t < 8; t++) lsum[t] = 0.f;
#pragma unroll
    for (int r = 0; r < 4; r++) {
        int rowt = rbase0 + r;
        int grow = blockRow + rowt;
        if (grow < M) {
            float rd = WRITE_NEXT ? (1.0f / deg[grow]) : 0.f;
#pragma unroll
            for (int t = 0; t < 8; t++) {
                int col = t * 16 + sub;
                float val = acc[t][r] + bias[col];
                val = (val > 0.f) ? val : NEG * val;
                lsum[t] += val;
                if (WRITE_NEXT) stg[rowt * 136 + col] = (bf16)(val * rd);
            }
        }
    }
#pragma unroll
    for (int t = 0; t < 8; t++) {
        lsum[t] += __shfl_xor(lsum[t], 16);
        lsum[t] += __shfl_xor(lsum[t], 32);
    }
    if (rg == 0) {
#pragma unroll
        for (int t = 0; t < 8; t++) atomicAdd(&cs[t * 16 + sub], lsum[t]);
    }
    __syncthreads();
    if (tid < 128) atomicAdd(&colsum[tid], cs[tid]);
    if (WRITE_NEXT) {
#pragma unroll
        for (int it = 0; it < 2; it++) {
            int s = it * 256 + tid;      // 0..511: 64 rows x 8 quads
            int row = s >> 3, q = s & 7;
            int grow = blockRow + row;
            if (grow < M) {
                float f[16];
#pragma unroll
                for (int k = 0; k < 16; k++) f[k] = (float)stg[row * 136 + q * 16 + k];
                hsout[(size_t)grow * 8 + q] = enc16(f);
            }
        }
    }
}

// ---------------- finisher ----------------

__global__ void k_final(const float* __restrict__ colsum, const float* __restrict__ Wpred,
                        const float* __restrict__ bpred, const float* __restrict__ Wcls,
                        const float* __restrict__ bcls, float* __restrict__ out, int n) {
    __shared__ float g[512];
    __shared__ float g2[128];
    __shared__ float lg[2];
    int t = threadIdx.x;  // 128 threads
    float invn = 1.0f / (float)n;
    for (int i = t; i < 512; i += 128) g[i] = colsum[i] * invn;
    __syncthreads();
    float acc = bpred[t];
    for (int i = 0; i < 512; i++) acc += g[i] * Wpred[i * 128 + t];
    g2[t] = acc;
    __syncthreads();
    if (t < 2) {
        float l = bcls[t];
        for (int j = 0; j < 128; j++) l += g2[j] * Wcls[j * 2 + t];
        lg[t] = l;
    }
    __syncthreads();
    if (t == 0) {
        float m = fmaxf(lg[0], lg[1]);
        float e0 = expf(lg[0] - m), e1 = expf(lg[1] - m);
        float s = e0 + e1;
        out[0] = e0 / s;
        out[1] = e1 / s;
    }
}

// ---------------- launch ----------------

extern "C" void kernel_launch(void* const* d_in, const int* in_sizes, int n_in,
                              void* d_out, int out_size, void* d_ws, size_t ws_size,
                              hipStream_t stream) {
    const float* node_feat = (const float*)d_in[0];
    const float* degree = (const float*)d_in[3];
    const float* Wn     = (const float*)d_in[4];
    const float* bn     = (const float*)d_in[5];
    const float* Wgcn   = (const float*)d_in[8];
    const float* bgcn   = (const float*)d_in[9];
    const float* Wpred  = (const float*)d_in[10];
    const float* bpred  = (const float*)d_in[11];
    const float* Wcls   = (const float*)d_in[12];
    const float* bcls   = (const float*)d_in[13];
    const int*   src    = (const int*)d_in[14];
    const int*   dst    = (const int*)d_in[15];
    float* out = (float*)d_out;

    const int N = in_sizes[3];
    const int E = in_sizes[14];
    (void)n_in; (void)out_size; (void)ws_size;

    char* p = (char*)d_ws;
    auto carve = [&](size_t bytes) { char* r = p; p += (bytes + 255) & ~(size_t)255; return r; };
    // cnt + colsum carved adjacently -> single memset covers both
    int*   cnt    = (int*)carve((size_t)N * 4);
    float* colsum = (float*)carve(512 * 4);
    uint4* h0g    = (uint4*)carve((size_t)N * H);       // fp8 h0 gather table (128 B/row)
    uint4* hsb0   = (uint4*)carve((size_t)N * H);       // fp8 pre-scaled hidden, ping
    uint4* hsb1   = (uint4*)carve((size_t)N * H);       // fp8 pre-scaled hidden, pong
    bf16*  WnT    = (bf16*)carve((size_t)256 * 128 * 2);
    bf16*  WgT    = (bf16*)carve((size_t)128 * 128 * 2);
    int*   row_ptr= (int*)carve((size_t)(N + 1) * 4);
    int*   nxt    = (int*)carve((size_t)N * 4);
    int*   ssrc   = (int*)carve((size_t)E * 4);
    int*   part   = (int*)carve(256 * 4);

    const int nblk = (N + 255) / 256;
    // zero cnt..colsum in one fill (contiguous carve region)
    hipMemsetAsync(cnt, 0, (size_t)((char*)(colsum + 512) - (char*)cnt), stream);

    // fused: in-degree histogram + weight pre-transpose
    k_setup<<<(E + 255) / 256, 256, 0, stream>>>(dst, cnt, E, Wn, Wgcn, WnT, WgT);
    k_scan1<<<nblk, 256, 0, stream>>>(cnt, part, N);
    k_scan23<<<nblk, 256, 0, stream>>>(cnt, part, row_ptr, nxt, N, E);

    const int gblk = (N + 63) / 64;
    const int ablk = (N + 15) / 16;
    const int fillBlks = (E + 255) / 256;

    // fused dispatch: bucket-fill (independent) + GEMM0 h0 = node_feat @ Wn + bn
    k_fillgemm0<<<fillBlks + gblk, 256, 0, stream>>>(src, dst, nxt, ssrc, E, fillBlks,
                                                     node_feat, WnT, bn, h0g, colsum, N);

    // fusion: hsb0[v] = (sum_{u->v} h0[u]) / deg[v]
    k_agg0<<<ablk, 256, 0, stream>>>(h0g, row_ptr, ssrc, degree, hsb0, N);

    // fused layers: (gather+self) -> gemm -> leakyrelu -> colsum (+ next hs, ping-pong
    // across dispatches — dispatch boundary = the only safe cross-XCD flush, per R13 lesson)
    k_gemmL<true ><<<gblk, 256, 0, stream>>>(hsb0, row_ptr, ssrc, degree, WgT, bgcn, hsb1, colsum + 1 * H, N);
    k_gemmL<true ><<<gblk, 256, 0, stream>>>(hsb1, row_ptr, ssrc, degree, WgT, bgcn, hsb0, colsum + 2 * H, N);
    k_gemmL<false><<<gblk, 256, 0, stream>>>(hsb0, row_ptr, ssrc, degree, WgT, bgcn, hsb1, colsum + 3 * H, N);

    k_final<<<1, 128, 0, stream>>>(colsum, Wpred, bpred, Wcls, bcls, out, N);
}